// Round 4
// baseline (68090.326 us; speedup 1.0000x reference)
//
#include <hip/hip_runtime.h>

#define NWG 256
#define WGS 512

typedef __attribute__((ext_vector_type(4))) float facc4;
typedef __attribute__((ext_vector_type(8))) short bfrag8;

#define MFMA_BF16 __builtin_amdgcn_mfma_f32_16x16x32_bf16

constexpr int B_ = 128, T_ = 512, I_ = 128, H_ = 1024;
constexpr int G_ = 4 * H_;  // 4096
constexpr int NG = 8, WPG = 32;  // 8 independent groups x 32 WGs x 16 batch rows

// ---------------- workspace layout (bytes) ----------------
constexpr size_t OFF_BARS = 0;                                   // 8 group bars @128B + init bar @1024
constexpr size_t OFF_H1F  = 4096;
constexpr size_t OFF_H2F  = OFF_H1F + 2ull * B_ * H_ * 4;
constexpr size_t OFF_C1   = OFF_H2F + 2ull * B_ * H_ * 4;
constexpr size_t OFF_C2   = OFF_C1 + (size_t)B_ * H_ * 4;
constexpr size_t OFF_X1F  = OFF_C2 + (size_t)B_ * H_ * 4;
constexpr size_t OFF_X2F  = OFF_X1F + (size_t)B_ * I_ * 4;
constexpr size_t OFF_H1S  = OFF_X2F + (size_t)B_ * H_ * 4;
constexpr size_t OFF_H2S  = OFF_H1S + 2ull * B_ * H_ * 2;
constexpr size_t OFF_X1S  = OFF_H2S + 2ull * B_ * H_ * 2;
constexpr size_t OFF_X2S  = OFF_X1S + (size_t)B_ * I_ * 2;
constexpr size_t OFF_BS1  = OFF_X2S + (size_t)B_ * H_ * 2;
constexpr size_t OFF_BS2  = OFF_BS1 + (size_t)G_ * 4;
constexpr size_t ZERO_BYTES = OFF_BS2 + (size_t)G_ * 4;
// bf16 weights (converted in-kernel each launch)
constexpr size_t OFF_WQ1  = ZERO_BYTES;                          // 3*I*H
constexpr size_t OFF_WR1  = OFF_WQ1 + 3ull * I_ * H_ * 2;        // 2*H*I
constexpr size_t OFF_WIH1 = OFF_WR1 + 2ull * H_ * I_ * 2;        // G*I
constexpr size_t OFF_WHH1 = OFF_WIH1 + (size_t)G_ * I_ * 2;      // G*H
constexpr size_t OFF_WQ2  = OFF_WHH1 + (size_t)G_ * H_ * 2;      // 3*H*H (L3-streamed)
constexpr size_t OFF_WR2  = OFF_WQ2 + 3ull * H_ * H_ * 2;        // 2*H*H
constexpr size_t OFF_WIH2 = OFF_WR2 + 2ull * H_ * H_ * 2;        // G*H
constexpr size_t OFF_WHH2 = OFF_WIH2 + (size_t)G_ * H_ * 2;      // G*H

__device__ __forceinline__ float sigf(float x) { return 1.0f / (1.0f + __expf(-x)); }

__device__ __forceinline__ unsigned short f2bf(float f) {
  union { float f; unsigned u; } v; v.f = f;
  unsigned r = v.u + 0x7FFFu + ((v.u >> 16) & 1u);  // RNE
  return (unsigned short)(r >> 16);
}

// ---------- device-coherent (sc0 sc1) data plane for cross-WG data ----------
__device__ __forceinline__ float cloadf(const float* p) {
  return __hip_atomic_load(p, __ATOMIC_RELAXED, __HIP_MEMORY_SCOPE_AGENT);
}
__device__ __forceinline__ void cstoref(float* p, float v) {
  __hip_atomic_store(p, v, __ATOMIC_RELAXED, __HIP_MEMORY_SCOPE_AGENT);
}
__device__ __forceinline__ void cstoreu(unsigned* p, unsigned v) {
  __hip_atomic_store(p, v, __ATOMIC_RELAXED, __HIP_MEMORY_SCOPE_AGENT);
}
__device__ __forceinline__ bfrag8 cload_frag(const unsigned short* p) {
  union { bfrag8 f; unsigned long long u[2]; } r;
  r.u[0] = __hip_atomic_load((const unsigned long long*)p, __ATOMIC_RELAXED,
                             __HIP_MEMORY_SCOPE_AGENT);
  r.u[1] = __hip_atomic_load(((const unsigned long long*)p) + 1, __ATOMIC_RELAXED,
                             __HIP_MEMORY_SCOPE_AGENT);
  return r.f;
}
// pack bf16 shadow pairs: even lane stores (v, neighbor v) as one u32
__device__ __forceinline__ void cstore_sh(unsigned short* base, size_t idx, float v, int lane) {
  float vo = __shfl_xor(v, 1);
  if (!(lane & 1)) {
    unsigned pk = (unsigned)f2bf(v) | ((unsigned)f2bf(vo) << 16);
    cstoreu((unsigned*)(base + idx), pk);
  }
}

// bulk coherent stage: rows x (C4*4) bf16 elements -> LDS (whole WG)
template <int C4>
__device__ __forceinline__ void stage_coh(unsigned short* lds, int ldsStride, int ldsColOff,
                                          const unsigned short* src, int srcStride, int rows) {
  const int total = rows * C4;
  for (int i = threadIdx.x; i < total; i += WGS) {
    int r = i / C4, q = (i % C4) * 4;
    unsigned long long v = __hip_atomic_load(
        (const unsigned long long*)(src + (size_t)r * srcStride + q),
        __ATOMIC_RELAXED, __HIP_MEMORY_SCOPE_AGENT);
    *(unsigned long long*)(lds + (size_t)r * ldsStride + ldsColOff + q) = v;
  }
}

// ---- per-group barrier: 32 arrivals on one line. bar[0]=cnt, bar[1]=gen.
// RELEASE on arrival drains this WG's coherent stores (they sit at L3 after);
// waiters' coherent loads read L3 directly -> no cache-maintenance fences.
__device__ __forceinline__ void gbar_grp(unsigned* bar) {
  __syncthreads();
  if (threadIdx.x == 0) {
    unsigned g = __hip_atomic_load(bar + 1, __ATOMIC_RELAXED, __HIP_MEMORY_SCOPE_AGENT);
    unsigned a = __hip_atomic_fetch_add(bar, 1u, __ATOMIC_RELEASE, __HIP_MEMORY_SCOPE_AGENT);
    if (a == WPG - 1) {
      __hip_atomic_store(bar, 0u, __ATOMIC_RELAXED, __HIP_MEMORY_SCOPE_AGENT);
      __hip_atomic_store(bar + 1, g + 1u, __ATOMIC_RELEASE, __HIP_MEMORY_SCOPE_AGENT);
    }
    while (__hip_atomic_load(bar + 1, __ATOMIC_RELAXED, __HIP_MEMORY_SCOPE_AGENT) == g)
      __builtin_amdgcn_s_sleep(1);
    asm volatile("" ::: "memory");
  }
  __syncthreads();
}

// ---- full-fence GLOBAL barrier: used ONCE after init (weights are plain stores)
__device__ __forceinline__ void gbar_init(unsigned* bar) {
  __syncthreads();
  if (threadIdx.x == 0) {
    __builtin_amdgcn_fence(__ATOMIC_RELEASE, "agent");
    unsigned g = __hip_atomic_load(bar + 1, __ATOMIC_RELAXED, __HIP_MEMORY_SCOPE_AGENT);
    unsigned a = __hip_atomic_fetch_add(bar, 1u, __ATOMIC_RELAXED, __HIP_MEMORY_SCOPE_AGENT);
    if (a == NWG - 1) {
      __hip_atomic_store(bar, 0u, __ATOMIC_RELAXED, __HIP_MEMORY_SCOPE_AGENT);
      __hip_atomic_store(bar + 1, g + 1u, __ATOMIC_RELEASE, __HIP_MEMORY_SCOPE_AGENT);
    }
    while (__hip_atomic_load(bar + 1, __ATOMIC_RELAXED, __HIP_MEMORY_SCOPE_AGENT) == g)
      __builtin_amdgcn_s_sleep(1);
    __builtin_amdgcn_fence(__ATOMIC_ACQUIRE, "agent");
  }
  __syncthreads();
}

// ---- mogrify unit (one group, 16 rows): 2 16x16 tiles, 8 waves = 2 slots x 4 K-roles.
// nt = (u*2+slot)&NTM keeps nt ≡ f(wg&7) -> XCD-exclusive weight rows.
template <int K, int NTM, bool WCOH>
__device__ __forceinline__ void mog_g(
    const unsigned short* __restrict__ A,     // bf16 [B][K] (coherent, group rows)
    const unsigned short* __restrict__ W,     // bf16 [N][K] (plain L2 / coherent if WCOH)
    const float* __restrict__ bias,
    const float* srcF, int srcStride,
    float* dstF, unsigned short* dstS, int N,
    int rowBase, int u, unsigned short* As, float (*red)[4][64]) {
  constexpr int LSTR = K + 8;
  const int tid = threadIdx.x, lane = tid & 63, wv = tid >> 6;
  const int slot = wv >> 2, role = wv & 3;
  const int nt = (u * 2 + slot) & NTM;
  const int l15 = lane & 15, lq = lane >> 4;

  stage_coh<K / 4>(As, LSTR, 0, A + (size_t)rowBase * K, K, 16);
  __syncthreads();

  const unsigned short* ap = As + l15 * LSTR + lq * 8;
  const unsigned short* wp = W + (size_t)(nt * 16 + l15) * K + lq * 8;
  constexpr int kq = K / 4;
  facc4 acc = {0.f, 0.f, 0.f, 0.f};
#pragma unroll
  for (int k = 0; k < kq; k += 32) {
    bfrag8 bv;
    if (WCOH) bv = cload_frag(wp + role * kq + k);
    else bv = *(const bfrag8*)(wp + role * kq + k);
    acc = MFMA_BF16(*(const bfrag8*)(ap + role * kq + k), bv, acc, 0, 0, 0);
  }
  red[wv][0][lane] = acc[0]; red[wv][1][lane] = acc[1];
  red[wv][2][lane] = acc[2]; red[wv][3][lane] = acc[3];
  __syncthreads();
  if (role == 0) {
    const int n = nt * 16 + l15;
    const float bn = bias[n];
#pragma unroll
    for (int j = 0; j < 4; j++) {
      float d = red[slot * 4 + 0][j][lane] + red[slot * 4 + 1][j][lane] +
                red[slot * 4 + 2][j][lane] + red[slot * 4 + 3][j][lane];
      const int m = rowBase + lq * 4 + j;
      float v = 2.0f * sigf(d + bn) * cloadf(&srcF[(size_t)m * srcStride + n]);
      cstoref(&dstF[(size_t)m * N + n], v);
      cstore_sh(dstS, (size_t)m * N + n, v, lane);
    }
  }
  __syncthreads();
}

// ---- LSTM cell unit (one group): 2 16x16 tiles over H, 8 waves = 2 slots x 4 gates,
// full K per wave (no partials). Weights plain (L2-resident via nt-slicing).
template <int KX>
__device__ __forceinline__ void cell_g(
    const unsigned short* __restrict__ X,    // [B][KX]
    const unsigned short* __restrict__ Hm,   // [B][1024]
    const unsigned short* __restrict__ Wih,  // [G][KX]
    const unsigned short* __restrict__ Whh,  // [G][1024]
    const float* __restrict__ bsum,
    float* c, float* hF, unsigned short* hS,
    int rowBase, int u, unsigned short* As, float (*red)[4][64]) {
  constexpr int LSTR = KX + 1024 + 8;
  const int tid = threadIdx.x, lane = tid & 63, wv = tid >> 6;
  const int slot = wv & 1, gate = wv >> 1;
  const int nt = (u * 2 + slot) & 63;
  const int l15 = lane & 15, lq = lane >> 4;

  stage_coh<KX / 4>(As, LSTR, 0, X + (size_t)rowBase * KX, KX, 16);
  stage_coh<256>(As, LSTR, KX, Hm + (size_t)rowBase * 1024, 1024, 16);
  __syncthreads();

  const unsigned short* ap = As + l15 * LSTR + lq * 8;
  const int wrow = gate * H_ + nt * 16 + l15;
  const unsigned short* wi = Wih + (size_t)wrow * KX + lq * 8;
  const unsigned short* wh = Whh + (size_t)wrow * 1024 + lq * 8;
  facc4 acc = {0.f, 0.f, 0.f, 0.f};
#pragma unroll
  for (int k = 0; k < KX; k += 32)
    acc = MFMA_BF16(*(const bfrag8*)(ap + k), *(const bfrag8*)(wi + k), acc, 0, 0, 0);
#pragma unroll 8
  for (int k = 0; k < 1024; k += 32)
    acc = MFMA_BF16(*(const bfrag8*)(ap + KX + k), *(const bfrag8*)(wh + k), acc, 0, 0, 0);
  red[wv][0][lane] = acc[0]; red[wv][1][lane] = acc[1];
  red[wv][2][lane] = acc[2]; red[wv][3][lane] = acc[3];
  __syncthreads();
  if (gate == 0) {
    const int n = nt * 16 + l15;
    const float bi = bsum[n], bf = bsum[H_ + n], bg = bsum[2 * H_ + n], bo = bsum[3 * H_ + n];
#pragma unroll
    for (int j = 0; j < 4; j++) {
      float iv = sigf(red[0 * 2 + slot][j][lane] + bi);
      float fv = sigf(red[1 * 2 + slot][j][lane] + bf);
      float gv = tanhf(red[2 * 2 + slot][j][lane] + bg);
      float ov = sigf(red[3 * 2 + slot][j][lane] + bo);
      const int m = rowBase + lq * 4 + j;
      const size_t idx = (size_t)m * H_ + n;
      float cold = cloadf(&c[idx]);
      float cn = fv * cold + iv * gv;
      float hn = ov * tanhf(cn);
      cstoref(&c[idx], cn);
      cstoref(&hF[idx], hn);
      cstore_sh(hS, idx, hn, lane);
    }
  }
  __syncthreads();
}

__global__ __launch_bounds__(WGS, 2) void moglstm_kernel(
    const float* __restrict__ in_seq,
    const float* __restrict__ c1Q, const float* __restrict__ c1Qb,
    const float* __restrict__ c1R, const float* __restrict__ c1Rb,
    const float* __restrict__ c1Wih, const float* __restrict__ c1Whh,
    const float* __restrict__ c1bih, const float* __restrict__ c1bhh,
    const float* __restrict__ c2Q, const float* __restrict__ c2Qb,
    const float* __restrict__ c2R, const float* __restrict__ c2Rb,
    const float* __restrict__ c2Wih, const float* __restrict__ c2Whh,
    const float* __restrict__ c2bih, const float* __restrict__ c2bhh,
    const float* __restrict__ linW, const float* __restrict__ linb,
    char* ws, float* __restrict__ out) {
  __shared__ float red[8][4][64];                    // 8 KB
  __shared__ unsigned short As[16 * (1024 + 1024 + 8)];  // 65.8 KB staging

  float* h1f0 = (float*)(ws + OFF_H1F);
  float* h1f1 = h1f0 + (size_t)B_ * H_;
  float* h2f0 = (float*)(ws + OFF_H2F);
  float* h2f1 = h2f0 + (size_t)B_ * H_;
  float* c1f = (float*)(ws + OFF_C1);
  float* c2f = (float*)(ws + OFF_C2);
  float* x1f = (float*)(ws + OFF_X1F);
  float* x2f = (float*)(ws + OFF_X2F);
  unsigned short* h1s0 = (unsigned short*)(ws + OFF_H1S);
  unsigned short* h1s1 = h1s0 + (size_t)B_ * H_;
  unsigned short* h2s0 = (unsigned short*)(ws + OFF_H2S);
  unsigned short* h2s1 = h2s0 + (size_t)B_ * H_;
  unsigned short* x1s = (unsigned short*)(ws + OFF_X1S);
  unsigned short* x2s = (unsigned short*)(ws + OFF_X2S);
  float* bs1 = (float*)(ws + OFF_BS1);
  float* bs2 = (float*)(ws + OFF_BS2);
  unsigned short* wq1 = (unsigned short*)(ws + OFF_WQ1);
  unsigned short* wr1 = (unsigned short*)(ws + OFF_WR1);
  unsigned short* wih1 = (unsigned short*)(ws + OFF_WIH1);
  unsigned short* whh1 = (unsigned short*)(ws + OFF_WHH1);
  unsigned short* wq2 = (unsigned short*)(ws + OFF_WQ2);
  unsigned short* wr2 = (unsigned short*)(ws + OFF_WR2);
  unsigned short* wih2 = (unsigned short*)(ws + OFF_WIH2);
  unsigned short* whh2 = (unsigned short*)(ws + OFF_WHH2);

  const int wg = blockIdx.x;
  const int g = wg >> 5;        // group 0..7 (16 batch rows each)
  const int lw = wg & 31;       // WG within group; lw&7 = XCD under round-robin
  const int rowBase = g * 16;
  unsigned* mybar = (unsigned*)(ws + OFF_BARS + 128 * g);
  unsigned* ibar = (unsigned*)(ws + OFF_BARS + 1024);

  // ---- init: fp32 -> bf16 weight conversion (plain stores) + bias sums
  {
    size_t gt = (size_t)wg * WGS + threadIdx.x;
    const size_t gs = (size_t)NWG * WGS;
    const float* srcs[8] = {c1Q, c1R, c1Wih, c1Whh, c2Q, c2R, c2Wih, c2Whh};
    unsigned short* dsts[8] = {wq1, wr1, wih1, whh1, wq2, wr2, wih2, whh2};
    const size_t cnts[8] = {3ull * I_ * H_, 2ull * H_ * I_, (size_t)G_ * I_,
                            (size_t)G_ * H_, 3ull * H_ * H_, 2ull * H_ * H_,
                            (size_t)G_ * H_, (size_t)G_ * H_};
    for (int a = 0; a < 8; a++)
      for (size_t i = gt; i < cnts[a]; i += gs) dsts[a][i] = f2bf(srcs[a][i]);
    for (size_t i = gt; i < (size_t)G_; i += gs) bs1[i] = c1bih[i] + c1bhh[i];
    for (size_t i = gt; i < (size_t)G_; i += gs) bs2[i] = c2bih[i] + c2bhh[i];
  }
  gbar_init(ibar);  // full fences ONCE: publish plain-stored weights

  // phase p: layer-1 step t=p and layer-2 step t=p-1 (per group, independent pace)
  static const int u1tab[6] = {4, 32, 4, 32, 4, 32};
  for (int p = 0; p <= T_; ++p) {
    const int q = p & 1;
    const int q2 = 1 - q;
    const bool doL1 = (p < T_);
    const bool doL2 = (p > 0);
    float* h1q = q ? h1f1 : h1f0;
    float* h1o = q ? h1f0 : h1f1;
    unsigned short* h1sq = q ? h1s1 : h1s0;
    unsigned short* h1so = q ? h1s0 : h1s1;
    float* h2q2 = q2 ? h2f1 : h2f0;
    float* h2o = q ? h2f1 : h2f0;
    unsigned short* h2sq2 = q2 ? h2s1 : h2s0;
    unsigned short* h2so = q ? h2s1 : h2s0;

    for (int s = 0; s < 6; ++s) {
      const int U2 = doL2 ? 32 : 0;
      const int U = U2 + (doL1 ? u1tab[s] : 0);
      for (int u = lw; u < U; u += WPG) {
        if (u < U2) {  // layer 2, step p-1
          switch (s) {
            case 0: mog_g<1024, 63, true>(h2sq2, wq2, c2Qb, h1q, H_, x2f, x2s, H_, rowBase, u, As, red); break;
            case 1: mog_g<1024, 63, false>(x2s, wr2, c2Rb, h2q2, H_, h2q2, h2sq2, H_, rowBase, u, As, red); break;
            case 2: mog_g<1024, 63, true>(h2sq2, wq2 + 1ull * H_ * H_, c2Qb + H_, x2f, H_, x2f, x2s, H_, rowBase, u, As, red); break;
            case 3: mog_g<1024, 63, false>(x2s, wr2 + 1ull * H_ * H_, c2Rb + H_, h2q2, H_, h2q2, h2sq2, H_, rowBase, u, As, red); break;
            case 4: mog_g<1024, 63, true>(h2sq2, wq2 + 2ull * H_ * H_, c2Qb + 2 * H_, x2f, H_, x2f, x2s, H_, rowBase, u, As, red); break;
            case 5: cell_g<1024>(x2s, h2sq2, wih2, whh2, bs2, c2f, h2o, h2so, rowBase, u, As, red); break;
          }
        } else {  // layer 1, step p
          const int v = u - U2;
          switch (s) {
            case 0: mog_g<1024, 7, false>(h1sq, wq1, c1Qb, in_seq + (size_t)p * I_, T_ * I_, x1f, x1s, I_, rowBase, v, As, red); break;
            case 1: mog_g<128, 63, false>(x1s, wr1, c1Rb, h1q, H_, h1q, h1sq, H_, rowBase, v, As, red); break;
            case 2: mog_g<1024, 7, false>(h1sq, wq1 + 1ull * I_ * H_, c1Qb + I_, x1f, I_, x1f, x1s, I_, rowBase, v, As, red); break;
            case 3: mog_g<128, 63, false>(x1s, wr1 + 1ull * H_ * I_, c1Rb + H_, h1q, H_, h1q, h1sq, H_, rowBase, v, As, red); break;
            case 4: mog_g<1024, 7, false>(h1sq, wq1 + 2ull * I_ * H_, c1Qb + 2 * I_, x1f, I_, x1f, x1s, I_, rowBase, v, As, red); break;
            case 5: cell_g<128>(x1s, h1sq, wih1, whh1, bs1, c1f, h1o, h1so, rowBase, v, As, red); break;
          }
        }
      }
      gbar_grp(mybar);
    }
  }

  // ---- final linear per group: out[rowBase+r] = dot(h2f0[row], linW) + linb
  if (lw == 0) {
    float* rf = (float*)red;
    const int tid = threadIdx.x;
    const int r = tid >> 5, cc = tid & 31;
    const float* row = h2f0 + (size_t)(rowBase + r) * H_ + cc * 32;
    const float* w = linW + cc * 32;
    float s = 0.f;
#pragma unroll
    for (int k = 0; k < 32; k++) s += cloadf(&row[k]) * w[k];
    rf[tid] = s;
    __syncthreads();
    if (tid < 16) {
      float acc = 0.f;
      for (int k = 0; k < 32; k++) acc += rf[tid * 32 + k];
      out[rowBase + tid] = acc + linb[0];
    }
  }
}

extern "C" void kernel_launch(void* const* d_in, const int* in_sizes, int n_in,
                              void* d_out, int out_size, void* d_ws, size_t ws_size,
                              hipStream_t stream) {
  const float* in_seq = (const float*)d_in[0];
  const float* c1Q = (const float*)d_in[1];
  const float* c1Qb = (const float*)d_in[2];
  const float* c1R = (const float*)d_in[3];
  const float* c1Rb = (const float*)d_in[4];
  const float* c1Wih = (const float*)d_in[5];
  const float* c1Whh = (const float*)d_in[6];
  const float* c1bih = (const float*)d_in[7];
  const float* c1bhh = (const float*)d_in[8];
  const float* c2Q = (const float*)d_in[9];
  const float* c2Qb = (const float*)d_in[10];
  const float* c2R = (const float*)d_in[11];
  const float* c2Rb = (const float*)d_in[12];
  const float* c2Wih = (const float*)d_in[13];
  const float* c2Whh = (const float*)d_in[14];
  const float* c2bih = (const float*)d_in[15];
  const float* c2bhh = (const float*)d_in[16];
  const float* linW = (const float*)d_in[17];
  const float* linb = (const float*)d_in[18];

  hipMemsetAsync(d_ws, 0, ZERO_BYTES, stream);
  moglstm_kernel<<<dim3(NWG), dim3(WGS), 0, stream>>>(
      in_seq, c1Q, c1Qb, c1R, c1Rb, c1Wih, c1Whh, c1bih, c1bhh,
      c2Q, c2Qb, c2R, c2Rb, c2Wih, c2Whh, c2bih, c2bhh,
      linW, linb, (char*)d_ws, (float*)d_out);
}